// Round 1
// baseline (137.755 us; speedup 1.0000x reference)
//
#include <hip/hip_runtime.h>

// BloomStageLoss: label-smoothed CE + transition penalty, scalar mean.
// B = 4194304 rows x C=5 fp32 logits + int32 targets -> 1 float.
// ~100 MB read => ~16 us floor at 6.3 TB/s.
//
// R4: fence/atomic removal confirmed (364->138us).
// R5: direct strided float4 loads beat LDS staging; no over-fetch (FETCH=50MB).
// R6 (this round): VALU diet. Algebraic collapse:
//   -0.875*lp_t - 0.025*sum(lp) = (m+ls) - 0.875*a_t - 0.025*sum(a)
// (coefficients of (m+ls) sum to exactly 1.0), computed in log2 domain so
// __expf pre-scales fuse, exact 1/s divide (12-op v_div_* chain) replaced by
// v_rcp_f32. ~112 -> ~60 VALU ops/row; div leaves the dependency chain.
// Loads and 2-kernel structure unchanged (settled by R4/R5 evidence).

constexpr int C = 5;
constexpr int BLOCK = 256;
constexpr int ROWS_PER_THREAD = 8;                    // 10 float4 per thread

__device__ __forceinline__ void row_terms(float a0, float a1, float a2,
                                          float a3, float a4, int t,
                                          float& Ks, float& Ps) {
    const float L = 1.44269504088896340736f;          // log2(e)
    // scaled logits (log2 domain)
    float s0 = a0 * L, s1 = a1 * L, s2 = a2 * L, s3 = a3 * L, s4 = a4 * L;
    float sm = fmaxf(fmaxf(fmaxf(s0, s1), fmaxf(s2, s3)), s4);  // -> v_max3 x2
    float e0 = exp2f(s0 - sm);                        // v_exp_f32, no pre-mul
    float e1 = exp2f(s1 - sm);
    float e2 = exp2f(s2 - sm);
    float e3 = exp2f(s3 - sm);
    float e4 = exp2f(s4 - sm);
    float se  = ((e0 + e1) + (e2 + e3)) + e4;
    float l2s = __log2f(se);                          // v_log_f32
    float inv = __builtin_amdgcn_rcpf(se);            // v_rcp_f32 (~1 ulp)
    float sa  = ((s0 + s1) + (s2 + s3)) + s4;
    float st  = (t == 0) ? s0 : (t == 1) ? s1 : (t == 2) ? s2
              : (t == 3) ? s3 : s4;
    // transition weights w_j = T[t][j]: d=|t-j| -> {0:0, 1:.5, 2:1, >=3:2}
    float tf = (float)t;
    float w0 = (tf > 2.5f) ? 2.0f : 0.5f * tf;        // d0 = tf
    float d1 = fabsf(tf - 1.0f); float w1 = (d1 > 2.5f) ? 2.0f : 0.5f * d1;
    float d2 = fabsf(tf - 2.0f); float w2 = (d2 > 2.5f) ? 2.0f : 0.5f * d2;
    float d3 = fabsf(tf - 3.0f); float w3 = (d3 > 2.5f) ? 2.0f : 0.5f * d3;
    float d4 = 4.0f - tf;        float w4 = (d4 > 2.5f) ? 2.0f : 0.5f * d4;
    float pn = fmaf(w4, e4, fmaf(w3, e3, fmaf(w2, e2, fmaf(w1, e1, w0 * e0))));
    // CE (log2 domain): K = (sm + log2 s) - 0.875*s_t - 0.025*sum(s)
    Ks += ((sm + l2s) - 0.875f * st) - 0.025f * sa;
    // penalty numerator * 1/s, summed across rows
    Ps = fmaf(pn, inv, Ps);
}

// 4 consecutive rows packed in 5 float4s
__device__ __forceinline__ void quad_terms(float4 v0, float4 v1, float4 v2,
                                           float4 v3, float4 v4, int4 t,
                                           float& Ks, float& Ps) {
    row_terms(v0.x, v0.y, v0.z, v0.w, v1.x, t.x, Ks, Ps);
    row_terms(v1.y, v1.z, v1.w, v2.x, v2.y, t.y, Ks, Ps);
    row_terms(v2.z, v2.w, v3.x, v3.y, v3.z, t.z, Ks, Ps);
    row_terms(v3.w, v4.x, v4.y, v4.z, v4.w, t.w, Ks, Ps);
}

__global__ __launch_bounds__(BLOCK) void bloom_partial(
        const float* __restrict__ x, const int* __restrict__ tgt,
        double* __restrict__ partial, int nGroups, int B) {
    const int tid = threadIdx.x;
    const int g = blockIdx.x * BLOCK + tid;   // 8-row group index
    float Ks = 0.0f, Ps = 0.0f;

    if (g < nGroups) {
        const float4* __restrict__ x4 = (const float4*)x;
        const int4* __restrict__ tgt4 = (const int4*)tgt;
        const long b4 = (long)g * 10;         // 8 rows * 5 floats = 10 float4
        // 12 independent loads issued back-to-back (deep MLP, no barrier)
        float4 v0 = x4[b4 + 0];
        float4 v1 = x4[b4 + 1];
        float4 v2 = x4[b4 + 2];
        float4 v3 = x4[b4 + 3];
        float4 v4 = x4[b4 + 4];
        float4 v5 = x4[b4 + 5];
        float4 v6 = x4[b4 + 6];
        float4 v7 = x4[b4 + 7];
        float4 v8 = x4[b4 + 8];
        float4 v9 = x4[b4 + 9];
        int4 ta = tgt4[(long)g * 2 + 0];
        int4 tb = tgt4[(long)g * 2 + 1];

        quad_terms(v0, v1, v2, v3, v4, ta, Ks, Ps);
        quad_terms(v5, v6, v7, v8, v9, tb, Ks, Ps);
    }

    // tail rows (B % ROWS_PER_THREAD*BLOCK) -> last block, scalar per row
    if (blockIdx.x == gridDim.x - 1) {
        for (int r = nGroups * ROWS_PER_THREAD + tid; r < B; r += BLOCK) {
            row_terms(x[(long)r * C + 0], x[(long)r * C + 1],
                      x[(long)r * C + 2], x[(long)r * C + 3],
                      x[(long)r * C + 4], tgt[r], Ks, Ps);
        }
    }

    // fold constants once per thread: loss = ln2*K + 0.1*pen
    float local = fmaf(0.69314718055994530942f, Ks, 0.1f * Ps);

    // block reduction; plain store (kernel boundary orders it before final)
    #pragma unroll
    for (int off = 32; off > 0; off >>= 1)
        local += __shfl_down(local, off, 64);
    __shared__ double wsum[4];
    const int lane = tid & 63;
    const int wid = tid >> 6;
    if (lane == 0) wsum[wid] = (double)local;
    __syncthreads();
    if (tid == 0)
        partial[blockIdx.x] = wsum[0] + wsum[1] + wsum[2] + wsum[3];
}

__global__ __launch_bounds__(BLOCK) void bloom_final(
        const double* __restrict__ partial, float* __restrict__ out,
        int nPartials, int B) {
    __shared__ double wsum[4];
    const int tid = threadIdx.x;
    double s = 0.0;
    for (int i = tid; i < nPartials; i += BLOCK)
        s += partial[i];
    #pragma unroll
    for (int off = 32; off > 0; off >>= 1)
        s += __shfl_down(s, off, 64);
    const int lane = tid & 63;
    const int wid = tid >> 6;
    if (lane == 0) wsum[wid] = s;
    __syncthreads();
    if (tid == 0)
        out[0] = (float)((wsum[0] + wsum[1] + wsum[2] + wsum[3]) / (double)B);
}

extern "C" void kernel_launch(void* const* d_in, const int* in_sizes, int n_in,
                              void* d_out, int out_size, void* d_ws, size_t ws_size,
                              hipStream_t stream) {
    const float* x = (const float*)d_in[0];
    const int* tgt = (const int*)d_in[1];
    float* out = (float*)d_out;

    int B = in_sizes[1];
    int nGroups = B / ROWS_PER_THREAD;                    // 8-row groups
    int blocks = (nGroups + BLOCK - 1) / BLOCK;           // 2048 for B=4M
    if (blocks < 1) blocks = 1;

    double* partial = (double*)d_ws;

    bloom_partial<<<blocks, BLOCK, 0, stream>>>(x, tgt, partial, nGroups, B);
    bloom_final<<<1, BLOCK, 0, stream>>>(partial, out, blocks, B);
}